// Round 1
// baseline (487.212 us; speedup 1.0000x reference)
//
#include <hip/hip_runtime.h>
#include <hip/hip_bf16.h>
#include <math.h>

typedef __attribute__((ext_vector_type(8))) short short8;
typedef __attribute__((ext_vector_type(4))) short short4_;
typedef __attribute__((ext_vector_type(4))) float f32x4;

#define MFMA16(a, b, c) __builtin_amdgcn_mfma_f32_16x16x32_bf16((a), (b), (c), 0, 0, 0)

// fp32 -> bf16 round-to-nearest-even
__device__ __forceinline__ short f2bf(float f) {
  union { float f; unsigned u; } v; v.f = f;
  unsigned r = v.u + 0x7fffu + ((v.u >> 16) & 1u);
  return (short)(r >> 16);
}

// ---------------------------------------------------------------------------
// GroupNorm: one block per (batch, group). 16 ch x 1024 spatial = 16384 elems.
// ---------------------------------------------------------------------------
__global__ __launch_bounds__(256) void gn_kernel(const float* __restrict__ x,
                                                 const float* __restrict__ gamma,
                                                 const float* __restrict__ beta,
                                                 float* __restrict__ out) {
  const int blk = blockIdx.x;  // b*16 + g
  const int t = threadIdx.x;
  const size_t base = (size_t)blk * 16384;
  const float4* xp = (const float4*)(x + base);
  float s = 0.f, q = 0.f;
  float4 vals[16];
  for (int i = 0; i < 16; ++i) {
    float4 v = xp[t + i * 256];
    vals[i] = v;
    s += v.x + v.y + v.z + v.w;
    q += v.x * v.x + v.y * v.y + v.z * v.z + v.w * v.w;
  }
  __shared__ float rs[256], rq[256];
  rs[t] = s; rq[t] = q;
  __syncthreads();
  for (int o = 128; o > 0; o >>= 1) {
    if (t < o) { rs[t] += rs[t + o]; rq[t] += rq[t + o]; }
    __syncthreads();
  }
  __shared__ float sh_mu, sh_inv;
  if (t == 0) {
    float mu = rs[0] * (1.f / 16384.f);
    float var = rq[0] * (1.f / 16384.f) - mu * mu;
    sh_mu = mu;
    sh_inv = rsqrtf(var + 1e-5f);
  }
  __syncthreads();
  const float mu = sh_mu, inv = sh_inv;
  const int g = blk & 15;
  float4* op = (float4*)(out + base);
  for (int i = 0; i < 16; ++i) {
    int f = t + i * 256;
    int c = (g << 4) + (f >> 8);  // channel = g*16 + f*4/1024
    float ga = gamma[c], be = beta[c];
    float4 v = vals[i], y;
    y.x = (v.x - mu) * inv * ga + be;
    y.y = (v.y - mu) * inv * ga + be;
    y.z = (v.z - mu) * inv * ga + be;
    y.w = (v.w - mu) * inv * ga + be;
    op[f] = y;
  }
}

// ---------------------------------------------------------------------------
// QKV GEMM: Y_bf16[b,m,n] = sum_k W_f32[m,k] * X_f32[b,k,n]; M=768,K=256,N=1024
// 128x128 tile / block, 4 waves of 64x64, BK=32 (one mfma K-step).
// ---------------------------------------------------------------------------
__global__ __launch_bounds__(256) void gemm_qkv_kernel(const float* __restrict__ W,
                                                       const float* __restrict__ X,
                                                       short* __restrict__ Y) {
  const int m0 = blockIdx.x * 128;
  const int n0 = blockIdx.y * 128;
  const int b = blockIdx.z;
  const int t = threadIdx.x;
  __shared__ short As[128][32];  // [m][k]
  __shared__ short Bs[128][32];  // [n][k] (transposed X tile)
  const int w = t >> 6, lane = t & 63, l15 = lane & 15, quad = lane >> 4;
  const int wm = (w >> 1) * 64, wn = (w & 1) * 64;
  f32x4 acc[4][4];
  for (int i = 0; i < 4; i++)
    for (int j = 0; j < 4; j++) acc[i][j] = (f32x4){0.f, 0.f, 0.f, 0.f};
  const int mm = t >> 1, half = (t & 1) * 16;
  const float* wrow = W + (size_t)(m0 + mm) * 256 + half;
  const size_t xbase = (size_t)b * 256 * 1024 + n0;

  for (int k0 = 0; k0 < 256; k0 += 32) {
    __syncthreads();
    {  // stage A (W slice) fp32 -> bf16
      const float* wp = wrow + k0;
      float4 a0 = *(const float4*)(wp);
      float4 a1 = *(const float4*)(wp + 4);
      float4 a2 = *(const float4*)(wp + 8);
      float4 a3 = *(const float4*)(wp + 12);
      short8 s0, s1;
      s0[0] = f2bf(a0.x); s0[1] = f2bf(a0.y); s0[2] = f2bf(a0.z); s0[3] = f2bf(a0.w);
      s0[4] = f2bf(a1.x); s0[5] = f2bf(a1.y); s0[6] = f2bf(a1.z); s0[7] = f2bf(a1.w);
      s1[0] = f2bf(a2.x); s1[1] = f2bf(a2.y); s1[2] = f2bf(a2.z); s1[3] = f2bf(a2.w);
      s1[4] = f2bf(a3.x); s1[5] = f2bf(a3.y); s1[6] = f2bf(a3.z); s1[7] = f2bf(a3.w);
      *(short8*)&As[mm][half] = s0;
      *(short8*)&As[mm][half + 8] = s1;
    }
    for (int p = 0; p < 4; ++p) {  // stage B transposed
      int kk = p * 8 + (t >> 5);
      int n4 = (t & 31) * 4;
      float4 xv = *(const float4*)(X + xbase + (size_t)(k0 + kk) * 1024 + n4);
      Bs[n4 + 0][kk] = f2bf(xv.x);
      Bs[n4 + 1][kk] = f2bf(xv.y);
      Bs[n4 + 2][kk] = f2bf(xv.z);
      Bs[n4 + 3][kk] = f2bf(xv.w);
    }
    __syncthreads();
    short8 af[4], bfr[4];
    for (int i = 0; i < 4; i++) af[i] = *(const short8*)&As[wm + i * 16 + l15][quad * 8];
    for (int j = 0; j < 4; j++) bfr[j] = *(const short8*)&Bs[wn + j * 16 + l15][quad * 8];
    for (int i = 0; i < 4; i++)
      for (int j = 0; j < 4; j++) acc[i][j] = MFMA16(af[i], bfr[j], acc[i][j]);
  }
  for (int i = 0; i < 4; i++)
    for (int j = 0; j < 4; j++) {
      int m = m0 + wm + i * 16 + quad * 4;
      int n = n0 + wn + j * 16 + l15;
      short* yp = Y + ((size_t)b * 768 + m) * 1024 + n;
      for (int r = 0; r < 4; r++) yp[(size_t)r * 1024] = f2bf(acc[i][j][r]);
    }
}

// ---------------------------------------------------------------------------
// Flash cross-attention. One block = (qtile of 64, head, batch). 4 waves,
// each wave owns 16 query rows. Q from Qsrc branch, K/V from KVsrc branch.
// qkv layout: [b, head*96 + {0:q,32:k,64:v} + d, s], bf16.
// ---------------------------------------------------------------------------
__global__ __launch_bounds__(256) void attn_kernel(const short* __restrict__ Qsrc,
                                                   const short* __restrict__ KVsrc,
                                                   short* __restrict__ AO) {
  const int qt = blockIdx.x, h = blockIdx.y, b = blockIdx.z;
  const int t = threadIdx.x;
  const int w = t >> 6, lane = t & 63, l15 = lane & 15, quad = lane >> 4;
  const int q0 = qt * 64;
  const size_t qbase = ((size_t)b * 768 + h * 96) * 1024;
  const size_t kbase = ((size_t)b * 768 + h * 96 + 32) * 1024;
  const size_t vbase = ((size_t)b * 768 + h * 96 + 64) * 1024;
  __shared__ short Qt_[64][32];     // [sq][d]
  __shared__ short Kt[64][32];      // [sk][d]
  __shared__ short Vt[32][64];      // [dv][sk]
  __shared__ short Pt[4][16][64];   // per-wave P tile [sq][sk]
  {  // stage Q (transpose d-major -> sq-major)
    int d = t & 31, sq = (t >> 5) * 8;
    short8 v = *(const short8*)(Qsrc + qbase + (size_t)d * 1024 + q0 + sq);
    for (int i = 0; i < 8; i++) Qt_[sq + i][d] = v[i];
  }
  __syncthreads();
  const short8 aq = *(const short8*)&Qt_[w * 16 + l15][quad * 8];
  float m_i[4], l_i[4];
  f32x4 accO[2];
  for (int r = 0; r < 4; r++) { m_i[r] = -1e30f; l_i[r] = 0.f; }
  accO[0] = (f32x4){0.f, 0.f, 0.f, 0.f};
  accO[1] = (f32x4){0.f, 0.f, 0.f, 0.f};
  const float scale = 0.0625f;  // 1/sqrt(256)

  for (int kt = 0; kt < 16; ++kt) {
    const int k0 = kt * 64;
    __syncthreads();  // all waves done reading Kt/Vt of previous tile
    {
      int d = t & 31, sk = (t >> 5) * 8;
      short8 v = *(const short8*)(KVsrc + kbase + (size_t)d * 1024 + k0 + sk);
      for (int i = 0; i < 8; i++) Kt[sk + i][d] = v[i];
      int dv = t >> 3, ch = (t & 7) * 8;
      *(short8*)&Vt[dv][ch] = *(const short8*)(KVsrc + vbase + (size_t)dv * 1024 + k0 + ch);
    }
    __syncthreads();
    // S = Q K^T  (16 sq x 64 sk per wave, 4 mfma)
    f32x4 sc[4];
    for (int j = 0; j < 4; j++) {
      short8 bk = *(const short8*)&Kt[j * 16 + l15][quad * 8];
      f32x4 z = (f32x4){0.f, 0.f, 0.f, 0.f};
      sc[j] = MFMA16(aq, bk, z);
    }
    // online softmax; row = quad*4 + r, cols spread over quad's 16 lanes
    float alpha[4], rowsum[4];
    for (int r = 0; r < 4; r++) {
      float mx = fmaxf(fmaxf(sc[0][r], sc[1][r]), fmaxf(sc[2][r], sc[3][r])) * scale;
      for (int off = 1; off < 16; off <<= 1) mx = fmaxf(mx, __shfl_xor(mx, off, 16));
      float mnew = fmaxf(m_i[r], mx);
      alpha[r] = __expf(m_i[r] - mnew);
      m_i[r] = mnew;
      rowsum[r] = 0.f;
    }
    for (int j = 0; j < 4; j++)
      for (int r = 0; r < 4; r++) {
        float p = __expf(sc[j][r] * scale - m_i[r]);
        rowsum[r] += p;
        Pt[w][quad * 4 + r][j * 16 + l15] = f2bf(p);
      }
    for (int r = 0; r < 4; r++) {
      float rsum = rowsum[r];
      for (int off = 1; off < 16; off <<= 1) rsum += __shfl_xor(rsum, off, 16);
      l_i[r] = l_i[r] * alpha[r] + rsum;
    }
    for (int dvt = 0; dvt < 2; dvt++)
      for (int r = 0; r < 4; r++) accO[dvt][r] *= alpha[r];
    __syncthreads();  // conservative: order Pt writes before reads
    // O += P V^T-layout  (A = P [sq][sk], B[k=sk][n=dv] = Vt[dv][sk])
    for (int kc = 0; kc < 2; kc++) {
      short8 ap = *(const short8*)&Pt[w][l15][kc * 32 + quad * 8];
      for (int dvt = 0; dvt < 2; dvt++) {
        short8 bv = *(const short8*)&Vt[dvt * 16 + l15][kc * 32 + quad * 8];
        accO[dvt] = MFMA16(ap, bv, accO[dvt]);
      }
    }
  }
  for (int dvt = 0; dvt < 2; dvt++)
    for (int r = 0; r < 4; r++) {
      float v = accO[dvt][r] / l_i[r];
      int sq = q0 + w * 16 + quad * 4 + r;
      int dv = dvt * 16 + l15;
      AO[((size_t)b * 256 + h * 32 + dv) * 1024 + sq] = f2bf(v);
    }
}

// ---------------------------------------------------------------------------
// Output GEMM: out_f32[b,m,n] = sum_k W[m,k]*X_bf16[b,k,n] + bias[m] + resid
// M=256, K=256, N=1024 per batch.
// ---------------------------------------------------------------------------
__global__ __launch_bounds__(256) void gemm_out_kernel(const float* __restrict__ W,
                                                       const short* __restrict__ X,
                                                       const float* __restrict__ bias,
                                                       const float* __restrict__ resid,
                                                       float* __restrict__ out) {
  const int m0 = blockIdx.x * 128;
  const int n0 = blockIdx.y * 128;
  const int b = blockIdx.z;
  const int t = threadIdx.x;
  __shared__ short As[128][32];
  __shared__ short Bs[128][32];
  const int w = t >> 6, lane = t & 63, l15 = lane & 15, quad = lane >> 4;
  const int wm = (w >> 1) * 64, wn = (w & 1) * 64;
  f32x4 acc[4][4];
  for (int i = 0; i < 4; i++)
    for (int j = 0; j < 4; j++) acc[i][j] = (f32x4){0.f, 0.f, 0.f, 0.f};
  const int mm = t >> 1, half = (t & 1) * 16;
  const float* wrow = W + (size_t)(m0 + mm) * 256 + half;
  const size_t xbase = (size_t)b * 256 * 1024 + n0;

  for (int k0 = 0; k0 < 256; k0 += 32) {
    __syncthreads();
    {
      const float* wp = wrow + k0;
      float4 a0 = *(const float4*)(wp);
      float4 a1 = *(const float4*)(wp + 4);
      float4 a2 = *(const float4*)(wp + 8);
      float4 a3 = *(const float4*)(wp + 12);
      short8 s0, s1;
      s0[0] = f2bf(a0.x); s0[1] = f2bf(a0.y); s0[2] = f2bf(a0.z); s0[3] = f2bf(a0.w);
      s0[4] = f2bf(a1.x); s0[5] = f2bf(a1.y); s0[6] = f2bf(a1.z); s0[7] = f2bf(a1.w);
      s1[0] = f2bf(a2.x); s1[1] = f2bf(a2.y); s1[2] = f2bf(a2.z); s1[3] = f2bf(a2.w);
      s1[4] = f2bf(a3.x); s1[5] = f2bf(a3.y); s1[6] = f2bf(a3.z); s1[7] = f2bf(a3.w);
      *(short8*)&As[mm][half] = s0;
      *(short8*)&As[mm][half + 8] = s1;
    }
    for (int p = 0; p < 4; ++p) {
      int kk = p * 8 + (t >> 5);
      int n4 = (t & 31) * 4;
      short4_ xv = *(const short4_*)(X + xbase + (size_t)(k0 + kk) * 1024 + n4);
      Bs[n4 + 0][kk] = xv[0];
      Bs[n4 + 1][kk] = xv[1];
      Bs[n4 + 2][kk] = xv[2];
      Bs[n4 + 3][kk] = xv[3];
    }
    __syncthreads();
    short8 af[4], bfr[4];
    for (int i = 0; i < 4; i++) af[i] = *(const short8*)&As[wm + i * 16 + l15][quad * 8];
    for (int j = 0; j < 4; j++) bfr[j] = *(const short8*)&Bs[wn + j * 16 + l15][quad * 8];
    for (int i = 0; i < 4; i++)
      for (int j = 0; j < 4; j++) acc[i][j] = MFMA16(af[i], bfr[j], acc[i][j]);
  }
  for (int i = 0; i < 4; i++)
    for (int j = 0; j < 4; j++) {
      int m = m0 + wm + i * 16 + quad * 4;
      int n = n0 + wn + j * 16 + l15;
      size_t off = ((size_t)b * 256 + m) * 1024 + n;
      for (int r = 0; r < 4; r++)
        out[off + (size_t)r * 1024] = acc[i][j][r] + bias[m + r] + resid[off + (size_t)r * 1024];
    }
}

// ---------------------------------------------------------------------------
extern "C" void kernel_launch(void* const* d_in, const int* in_sizes, int n_in,
                              void* d_out, int out_size, void* d_ws, size_t ws_size,
                              hipStream_t stream) {
  const float* xA = (const float*)d_in[0];
  const float* xB = (const float*)d_in[1];
  const float* gA = (const float*)d_in[2];
  const float* bA = (const float*)d_in[3];
  const float* gB = (const float*)d_in[4];
  const float* bB = (const float*)d_in[5];
  const float* WqkvA = (const float*)d_in[6];
  const float* WqkvB = (const float*)d_in[7];
  const float* WoutA = (const float*)d_in[8];
  const float* boutA = (const float*)d_in[9];
  const float* WoutB = (const float*)d_in[10];
  const float* boutB = (const float*)d_in[11];
  float* out = (float*)d_out;
  char* ws = (char*)d_ws;
  // workspace layout (96 MB total)
  float* nA = (float*)(ws);                    // 16 MB fp32 norm A
  float* nB = (float*)(ws + 16777216);         // 16 MB fp32 norm B
  short* qkvA = (short*)(ws + 33554432);       // 24 MB bf16 qkv A
  short* qkvB = (short*)(ws + 58720256);       // 24 MB bf16 qkv B
  short* aoA = (short*)(ws + 83886080);        // 8 MB bf16 attn-out A
  short* aoB = (short*)(ws + 92274688);        // 8 MB bf16 attn-out B

  gn_kernel<<<256, 256, 0, stream>>>(xA, gA, bA, nA);
  gn_kernel<<<256, 256, 0, stream>>>(xB, gB, bB, nB);
  gemm_qkv_kernel<<<dim3(6, 8, 16), 256, 0, stream>>>(WqkvA, nA, qkvA);
  gemm_qkv_kernel<<<dim3(6, 8, 16), 256, 0, stream>>>(WqkvB, nB, qkvB);
  // branch A output: attn(qB -> kA,vA); branch B: attn(qA -> kB,vB)
  attn_kernel<<<dim3(16, 8, 16), 256, 0, stream>>>(qkvB, qkvA, aoA);
  attn_kernel<<<dim3(16, 8, 16), 256, 0, stream>>>(qkvA, qkvB, aoB);
  gemm_out_kernel<<<dim3(2, 8, 16), 256, 0, stream>>>(WoutA, aoA, boutA, nA, out);
  gemm_out_kernel<<<dim3(2, 8, 16), 256, 0, stream>>>(WoutB, aoB, boutB, nB, out + 4194304);
}